// Round 1
// 304.851 us; speedup vs baseline: 1.0571x; 1.0571x over previous
//
#include <hip/hip_runtime.h>

#define NN 64
#define IND 256
#define NH 8
#define OD 32

__device__ __forceinline__ unsigned f2bf(float f) {
  unsigned u = __float_as_uint(f);
  return (u + (((u >> 16) & 1u) + 0x7fffu)) >> 16;  // RNE
}
__device__ __forceinline__ float bflo(unsigned u) { return __uint_as_float(u << 16); }
__device__ __forceinline__ float bfhi(unsigned u) { return __uint_as_float(u & 0xffff0000u); }

// V[h][k] = sum_d W[k, h*32+d] * Watt[h, d]   (8 x 256)
__global__ __launch_bounds__(256) void precompute_v(
    const float* __restrict__ W, const float* __restrict__ Watt, float* __restrict__ V) {
  int tid = blockIdx.x * 256 + threadIdx.x;
  if (tid >= IND * NH) return;
  int h = tid >> 8, k = tid & 255;
  float acc = 0.f;
#pragma unroll
  for (int d = 0; d < OD; ++d) acc += W[k * 256 + h * OD + d] * Watt[h * OD + d];
  V[h * 256 + k] = acc;
}

// LDS layout (bytes):
//  [0,     33792)  s bf16 [64][264] (row = 132 words -> 4-bank shift/row)
//                  overlay post-barrier-1: yp float [32][260]  (33280 B)
//  [33792, 42112)  v float [8][260]
//                  overlay post-barrier-1: alpha float [512]
//                  overlay post-barrier-2: pp float [4][256]
//  [42112, 44160)  e float [512]
#define V_OFF 33792
#define E_OFF (V_OFF + 8320)
#define SMEM_BYTES (E_OFF + 2048)

__global__ __launch_bounds__(256, 3) void gat_fused(
    const float* __restrict__ Xi, const float* __restrict__ Xj,
    const float* __restrict__ W, const float* __restrict__ V,
    float* __restrict__ out) {
  __shared__ __align__(16) unsigned char smem[SMEM_BYTES];
  unsigned* s_pk = (unsigned*)smem;
  float* v_f = (float*)(smem + V_OFF);
  float* e_f = (float*)(smem + E_OFF);
  float* alpha_f = v_f;            // overlay: valid after barrier 1 (v dead)
  float* pp_f = v_f;               // overlay: valid after barrier 2 (alpha dead)
  float* yp_f = (float*)smem;      // overlay: valid after barrier 1 (s dead)

  const int t = threadIdx.x;
  const int b = blockIdx.x;
  const int w = t >> 6, l = t & 63;
  const int g = l >> 3, h = l & 7;

  // wave w owns rows [16w, 16w+16) end-to-end (loads, s-rows, e, alpha, C)
  const float4* Xi4 = (const float4*)Xi + (size_t)b * (NN * IND / 4) + w * 1024;
  const float4* Xj4 = (const float4*)Xj + (size_t)b * (NN * IND / 4) + w * 1024;

  // stage V into LDS [8][260] — redundantly per wave (identical values, so the
  // benign overlap with other waves' reads/writes is safe); keeps Phase B wave-local.
  {
    const float4* V4 = (const float4*)V;
    float4 vs[8];
#pragma unroll
    for (int r = 0; r < 8; ++r) vs[r] = V4[r * 64 + l];
#pragma unroll
    for (int r = 0; r < 8; ++r) *(float4*)(v_f + r * 260 + 4 * l) = vs[r];
  }

  // Phase A: issue ALL 32 global dwordx4 loads before any use (deep vmcnt pipe),
  // then pack s = Xi+Xj as bf16 into this wave's own s-rows.
  float4 xj[16], xi[16];
#pragma unroll
  for (int i = 0; i < 16; ++i) {
    xj[i] = Xj4[i * 64 + l];
    xi[i] = Xi4[i * 64 + l];
  }
#pragma unroll
  for (int i = 0; i < 16; ++i) {
    float4 a = xj[i], c = xi[i];
    unsigned p0 = f2bf(a.x + c.x) | (f2bf(a.y + c.y) << 16);
    unsigned p1 = f2bf(a.z + c.z) | (f2bf(a.w + c.w) << 16);
    *(uint2*)(s_pk + (w * 16 + i) * 132 + l * 2) = make_uint2(p0, p1);
  }

  // Phase B: e[n][h] = leakyrelu(s[n,:].V[h,:]) for own rows only — NO barrier
  // needed (intra-wave LDS dependency, ordered by lgkmcnt).
  float er[2];
#pragma unroll
  for (int pp = 0; pp < 2; ++pp) {
    int n = w * 16 + g + 8 * pp;
    const uint4* srow = (const uint4*)(s_pk + n * 132);
    const float4* vrow = (const float4*)(v_f + h * 260);
    float acc = 0.f;
#pragma unroll 8
    for (int kk = 0; kk < 32; ++kk) {
      uint4 sp = srow[kk];
      float4 va = vrow[2 * kk], vb = vrow[2 * kk + 1];
      acc += bflo(sp.x) * va.x + bfhi(sp.x) * va.y + bflo(sp.y) * va.z + bfhi(sp.y) * va.w
           + bflo(sp.z) * vb.x + bfhi(sp.z) * vb.y + bflo(sp.w) * vb.z + bfhi(sp.w) * vb.w;
    }
    er[pp] = acc >= 0.f ? acc : 0.2f * acc;
    e_f[n * 8 + h] = er[pp];    // addresses = 128w + 64pp + l : contiguous, conflict-free
  }
  __syncthreads();  // barrier 1: e complete; s and v globally dead past this point

  // softmax over n per h: computed redundantly by EVERY wave (butterfly over the
  // 8 lane-groups) — removes the serial t<64 section and its barrier.
  float m = -3.4e38f;
#pragma unroll
  for (int q = 0; q < 8; ++q) m = fmaxf(m, e_f[(g * 8 + q) * 8 + h]);
  m = fmaxf(m, __shfl_xor(m, 8, 64));
  m = fmaxf(m, __shfl_xor(m, 16, 64));
  m = fmaxf(m, __shfl_xor(m, 32, 64));
  float ssum = 0.f;
#pragma unroll
  for (int q = 0; q < 8; ++q) ssum += __expf(e_f[(g * 8 + q) * 8 + h] - m);
  ssum += __shfl_xor(ssum, 8, 64);
  ssum += __shfl_xor(ssum, 16, 64);
  ssum += __shfl_xor(ssum, 32, 64);
  float rinv = 1.f / ssum;

  // alpha for own rows (e value still in regs); consumed only by this wave's C.
#pragma unroll
  for (int pp = 0; pp < 2; ++pp) {
    int n = w * 16 + g + 8 * pp;
    alpha_f[n * 8 + h] = __expf(er[pp] - m) * rinv;
  }

  // Phase C: y partials from register-held xj; alpha reads are wave-local
  // broadcasts — NO barrier needed.
  float4 acc4[8];
#pragma unroll
  for (int hh = 0; hh < 8; ++hh) acc4[hh] = make_float4(0.f, 0.f, 0.f, 0.f);
#pragma unroll
  for (int i = 0; i < 16; ++i) {
    int n = w * 16 + i;
    float4 a0 = *(const float4*)(alpha_f + n * 8);
    float4 a1 = *(const float4*)(alpha_f + n * 8 + 4);
    float al[8] = {a0.x, a0.y, a0.z, a0.w, a1.x, a1.y, a1.z, a1.w};
    float4 x = xj[i];
#pragma unroll
    for (int hh = 0; hh < 8; ++hh) {
      acc4[hh].x += al[hh] * x.x;
      acc4[hh].y += al[hh] * x.y;
      acc4[hh].z += al[hh] * x.z;
      acc4[hh].w += al[hh] * x.w;
    }
  }
#pragma unroll
  for (int hh = 0; hh < 8; ++hh)
    *(float4*)(yp_f + (w * 8 + hh) * 260 + 4 * l) = acc4[hh];  // stride 260: h-reads conflict-free
  __syncthreads();  // barrier 2: yp complete

  // Epilogue: out[c] = elu(y[h(c)] . W[:,c]). k split across waves, 4 columns
  // per lane via float4 W loads (64x16B instead of 256x4B per thread), 4-wave
  // partials reduced via LDS. yp 4-partial sum reads: 8 distinct rows at
  // stride-260 words -> 8 distinct banks, lanes within an h-group broadcast.
  {
    const float* ypb = yp_f + g * 260;          // g == (4l)>>5 == head of columns 4l..4l+3
    const float4* W4 = (const float4*)W;        // W4[k*64 + l] = W[k][4l..4l+3]
    float4 acc = make_float4(0.f, 0.f, 0.f, 0.f);
    int k0 = w * 64;
#pragma unroll 8
    for (int kk = 0; kk < 64; ++kk) {
      int k = k0 + kk;
      float yv = ypb[k] + ypb[2080 + k] + ypb[4160 + k] + ypb[6240 + k];
      float4 wv = W4[k * 64 + l];
      acc.x += yv * wv.x;
      acc.y += yv * wv.y;
      acc.z += yv * wv.z;
      acc.w += yv * wv.w;
    }
    *(float4*)(pp_f + w * 256 + 4 * l) = acc;
  }
  __syncthreads();  // barrier 3: partials complete

  {
    float s = pp_f[t] + pp_f[256 + t] + pp_f[512 + t] + pp_f[768 + t];
    out[(size_t)b * 256 + t] = s > 0.f ? s : (__expf(s) - 1.f);
  }
}

extern "C" void kernel_launch(void* const* d_in, const int* in_sizes, int n_in,
                              void* d_out, int out_size, void* d_ws, size_t ws_size,
                              hipStream_t stream) {
  const float* Xi = (const float*)d_in[0];
  const float* Xj = (const float*)d_in[1];
  const float* W = (const float*)d_in[2];
  const float* Watt = (const float*)d_in[3];
  float* out = (float*)d_out;
  float* V = (float*)d_ws;  // 2048 floats
  int B = in_sizes[0] / (NN * IND);
  precompute_v<<<(IND * NH + 255) / 256, 256, 0, stream>>>(W, Watt, V);
  gat_fused<<<B, 256, 0, stream>>>(Xi, Xj, W, V, out);
}